// Round 2
// baseline (854.405 us; speedup 1.0000x reference)
//
#include <hip/hip_runtime.h>
#include <cmath>

// RecurrentGCN: GATv2Conv -> GConvGRU(1 step, H0=0) -> per-node MLP.
// Algebraic simplifications (verified against reference):
//  * H0=0  => cheb(H,...)=bias only; R unused (R*H=0); H_new=(1-Z)*Ht
//  * Z = sigmoid(cheb(h,W[0],b[0]) + b[1]);  Ht = tanh(cheb(h,W[4],b[4]) + b[5])
//  * both chebs share Tx0..Tx3 (3 sparse matvecs total)
//  * MLPAggregation: out[k>0] = relu(H[k-1]@W1[:16]+b1)@W2+b2 ; out[0] from H=0
// Strategy: build CSR by dst once (2 int atomics/edge); every segment op is an
// atomic-free per-node gather with 16 lanes/node. Matvec+Cheb-combine fused;
// GAT softmax prep+apply fused (same CSR segment, two passes, L2-warm).
// Cheb matvec inputs pre-scaled by dinv to kill the per-edge dinv gather.

constexpr int N = 50000;
constexpr int E = 1600000;

// ---------------- xl = x@Wl+bl, xr = x@Wr+br ----------------
__global__ __launch_bounds__(256)
void k_node_transform(const float* __restrict__ x,
                      const float* __restrict__ Wl, const float* __restrict__ bl,
                      const float* __restrict__ Wr, const float* __restrict__ br,
                      float* __restrict__ xl, float* __restrict__ xr) {
    __shared__ float sWl[128 * 16];
    __shared__ float sWr[128 * 16];
    int t = threadIdx.x;
    for (int i = t; i < 2048; i += 256) { sWl[i] = Wl[i]; sWr[i] = Wr[i]; }
    __syncthreads();
    int f = t & 15, nl = t >> 4;
    int n = blockIdx.x * 16 + nl;            // grid = N/16 exact (3125)
    const float4* xv = reinterpret_cast<const float4*>(x + (size_t)n * 128);
    float aL = bl[f], aR = br[f];
#pragma unroll 8
    for (int k4 = 0; k4 < 32; ++k4) {
        float4 v = xv[k4];
        int k = k4 * 4;
        aL += v.x * sWl[(k + 0) * 16 + f]; aR += v.x * sWr[(k + 0) * 16 + f];
        aL += v.y * sWl[(k + 1) * 16 + f]; aR += v.y * sWr[(k + 1) * 16 + f];
        aL += v.z * sWl[(k + 2) * 16 + f]; aR += v.z * sWr[(k + 2) * 16 + f];
        aL += v.w * sWl[(k + 3) * 16 + f]; aR += v.w * sWr[(k + 3) * 16 + f];
    }
    xl[n * 16 + f] = aL;
    xr[n * 16 + f] = aR;
}

// ---------------- in-degree (all edges) + out-degree (non-self) ----------------
__global__ __launch_bounds__(256)
void k_hist(const int* __restrict__ ei, int* __restrict__ cnt_in, int* __restrict__ deg_out) {
    int e = blockIdx.x * 256 + threadIdx.x;  // grid = E/256 exact
    int s = ei[e], d = ei[E + e];
    atomicAdd(&cnt_in[d], 1);
    if (s != d) atomicAdd(&deg_out[s], 1);
}

// ---------------- exclusive scan of cnt_in -> rowptr (single block) ----------------
__global__ __launch_bounds__(1024)
void k_scan(const int* __restrict__ cnt, int* __restrict__ rowptr, int n) {
    __shared__ int ssum[1024];
    int t = threadIdx.x;
    int chunk = (n + 1023) / 1024;
    int lo = t * chunk;
    int hi = lo + chunk; if (hi > n) hi = n; if (lo > n) lo = n;
    int s = 0;
    for (int i = lo; i < hi; ++i) s += cnt[i];
    ssum[t] = s;
    __syncthreads();
    for (int off = 1; off < 1024; off <<= 1) {
        int v = (t >= off) ? ssum[t - off] : 0;
        __syncthreads();
        ssum[t] += v;
        __syncthreads();
    }
    int prefix = (t == 0) ? 0 : ssum[t - 1];
    for (int i = lo; i < hi; ++i) { rowptr[i] = prefix; prefix += cnt[i]; }
    if (t == 0) rowptr[n] = ssum[1023];
}

// ---------------- per-edge alpha + CSR placement ----------------
__global__ __launch_bounds__(256)
void k_edge_alpha(const int* __restrict__ ei, const float* __restrict__ ea,
                  const float* __restrict__ xl, const float* __restrict__ xr,
                  const float* __restrict__ We, const float* __restrict__ att,
                  const int* __restrict__ rowptr, int* __restrict__ ctr,
                  int* __restrict__ ssrc, float* __restrict__ salpha,
                  int* __restrict__ seid) {
    __shared__ float sWe[256];
    __shared__ float satt[16];
    int t = threadIdx.x;
    sWe[t] = We[t];
    if (t < 16) satt[t] = att[t];
    __syncthreads();
    int e = blockIdx.x * 256 + t;            // grid = E/256 exact (6250)
    int s = ei[e], d = ei[E + e];
    const float4* ea4 = reinterpret_cast<const float4*>(ea + (size_t)e * 16);
    float a[16];
#pragma unroll
    for (int j = 0; j < 4; ++j) {
        float4 v = ea4[j];
        a[4 * j] = v.x; a[4 * j + 1] = v.y; a[4 * j + 2] = v.z; a[4 * j + 3] = v.w;
    }
    const float4* xl4 = reinterpret_cast<const float4*>(xl + (size_t)s * 16);
    const float4* xr4 = reinterpret_cast<const float4*>(xr + (size_t)d * 16);
    float xls[16], xrd[16];
#pragma unroll
    for (int j = 0; j < 4; ++j) {
        float4 L = xl4[j], R = xr4[j];
        xls[4 * j] = L.x; xls[4 * j + 1] = L.y; xls[4 * j + 2] = L.z; xls[4 * j + 3] = L.w;
        xrd[4 * j] = R.x; xrd[4 * j + 1] = R.y; xrd[4 * j + 2] = R.z; xrd[4 * j + 3] = R.w;
    }
    float alpha = 0.f;
#pragma unroll
    for (int f = 0; f < 16; ++f) {
        float em = 0.f;
#pragma unroll
        for (int j = 0; j < 16; ++j) em += a[j] * sWe[j * 16 + f];
        float m = xls[f] + xrd[f] + em;
        m = m > 0.f ? m : 0.2f * m;          // leaky_relu 0.2
        alpha += m * satt[f];
    }
    int p = rowptr[d] + atomicAdd(&ctr[d], 1);
    ssrc[p] = s; salpha[p] = alpha; seid[p] = e;
}

// ---- fused per-node GAT: ea_mean -> loop alpha -> amax -> softmax sum -> h,
//      hs = dinv*h, acc init = h@W[·][0], dinv ----
__global__ __launch_bounds__(256)
void k_gat(const int* __restrict__ rowptr, const int* __restrict__ ssrc,
           const int* __restrict__ seid, const float* __restrict__ salpha,
           const float* __restrict__ ea, const float* __restrict__ xl,
           const float* __restrict__ xr, const float* __restrict__ We,
           const float* __restrict__ att, const int* __restrict__ deg_out,
           const float* __restrict__ gat_bias,
           const float* __restrict__ Wz0, const float* __restrict__ Wh0,
           float* __restrict__ h, float* __restrict__ hs,
           float* __restrict__ accz, float* __restrict__ acch,
           float* __restrict__ dinv) {
    __shared__ float sWe[256], sWz[256], sWh[256];
    __shared__ float satt[16];
    __shared__ float sbuf[16][17];
    int t = threadIdx.x;
    sWe[t] = We[t]; sWz[t] = Wz0[t]; sWh[t] = Wh0[t];
    if (t < 16) satt[t] = att[t];
    int f = t & 15, nl = t >> 4;
    int n = blockIdx.x * 16 + nl;            // grid = N/16 exact
    int lo = rowptr[n], hi = rowptr[n + 1];
    // pass 1: ea row-sum (lane f reads byte f of each 64B row -> coalesced) + amax
    float sum = 0.f, amax = -3.0e38f;
    for (int i = lo; i < hi; ++i) {
        sum += ea[(size_t)seid[i] * 16 + f];
        amax = fmaxf(amax, salpha[i]);       // broadcast load, identical in group
    }
    float cnt = (float)(hi - lo);
    sbuf[nl][f] = sum / fmaxf(cnt, 1.f);     // ea_mean
    __syncthreads();
    float em = 0.f;
#pragma unroll
    for (int j = 0; j < 16; ++j) em += sbuf[nl][j] * sWe[j * 16 + f];
    float m = xl[n * 16 + f] + xr[n * 16 + f] + em;
    m = m > 0.f ? m : 0.2f * m;
    float c = m * satt[f];
#pragma unroll
    for (int off = 1; off < 16; off <<= 1) c += __shfl_xor(c, off, 64);
    float aloop = c;                          // self-loop alpha, all 16 lanes agree
    amax = fmaxf(amax, aloop);                // segment max incl. self-loop
    // pass 2: softmax-weighted sum over incoming edges (salpha L2-warm)
    float num = 0.f, den = 0.f;
    for (int i = lo; i < hi; ++i) {
        float ex = expf(salpha[i] - amax);
        int s = ssrc[i];
        num += ex * xl[s * 16 + f];
        den += ex;
    }
    float exl = expf(aloop - amax);
    num += exl * xl[n * 16 + f];
    den += exl;
    float hv = num / (den + 1e-16f) + gat_bias[f];
    float dg = (float)deg_out[n];
    float di = dg > 0.f ? rsqrtf(dg) : 0.f;
    h[n * 16 + f] = hv;
    hs[n * 16 + f] = di * hv;                 // pre-scaled for cheb matvec
    if (f == 0) dinv[n] = di;
    __syncthreads();                          // reuse sbuf
    sbuf[nl][f] = hv;
    __syncthreads();
    float az = 0.f, ah = 0.f;
#pragma unroll
    for (int j = 0; j < 16; ++j) {
        float v = sbuf[nl][j];
        az += v * sWz[j * 16 + f];
        ah += v * sWh[j * 16 + f];
    }
    accz[n * 16 + f] = az;
    acch[n * 16 + f] = ah;
}

// ---- fused Cheb step: mv[n] = -dinv[n]*sum_{s!=n} Tins[s];
//      tv = mode ? 2*mv - Tprev : mv; optional stores; acc += tv@W[k] ----
__global__ __launch_bounds__(256)
void k_mvcomb(const int* __restrict__ rowptr, const int* __restrict__ ssrc,
              const float* __restrict__ dinv, const float* __restrict__ Tins,
              const float* __restrict__ Tprev, float* __restrict__ Tstore,
              float* __restrict__ Tscale_store,
              const float* __restrict__ Wzk, const float* __restrict__ Whk,
              float* __restrict__ accz, float* __restrict__ acch, int mode) {
    __shared__ float sWz[256], sWh[256];
    __shared__ float st[16][17];
    int t = threadIdx.x;
    sWz[t] = Wzk[t]; sWh[t] = Whk[t];
    int f = t & 15, nl = t >> 4;
    int n = blockIdx.x * 16 + nl;            // grid = N/16 exact
    int lo = rowptr[n], hi = rowptr[n + 1];
    float acc = 0.f;
    for (int i = lo; i < hi; ++i) {
        int s = ssrc[i];
        if (s != n) acc += Tins[s * 16 + f]; // Tins already dinv-scaled
    }
    float di = dinv[n];
    float tv = -di * acc;
    if (mode) tv = 2.f * tv - Tprev[n * 16 + f];
    if (Tstore)       Tstore[n * 16 + f] = tv;
    if (Tscale_store) Tscale_store[n * 16 + f] = di * tv;
    st[nl][f] = tv;
    __syncthreads();
    float az = accz[n * 16 + f], ah = acch[n * 16 + f];
#pragma unroll
    for (int j = 0; j < 16; ++j) {
        float v = st[nl][j];
        az += v * sWz[j * 16 + f];
        ah += v * sWh[j * 16 + f];
    }
    accz[n * 16 + f] = az;
    acch[n * 16 + f] = ah;
}

// ---------------- GRU combine + per-node MLP ----------------
__global__ __launch_bounds__(256)
void k_final(const float* __restrict__ accz, const float* __restrict__ acch,
             const float* __restrict__ cheb_b,
             const float* __restrict__ W1, const float* __restrict__ b1,
             const float* __restrict__ W2, const float* __restrict__ b2,
             float* __restrict__ out) {
    int r = blockIdx.x * 256 + threadIdx.x;  // r in [0, N]
    if (r > N) return;
    float H[16];
    if (r == 0) {
#pragma unroll
        for (int j = 0; j < 16; ++j) H[j] = 0.f;
    } else {
        int n = r - 1;
#pragma unroll
        for (int j = 0; j < 16; ++j) {
            float z = accz[n * 16 + j] + cheb_b[0 * 16 + j] + cheb_b[1 * 16 + j];
            z = 1.f / (1.f + expf(-z));
            float ht = tanhf(acch[n * 16 + j] + cheb_b[4 * 16 + j] + cheb_b[5 * 16 + j]);
            H[j] = (1.f - z) * ht;           // Z*H0 + (1-Z)*Ht with H0=0
        }
    }
    float hid[4];
#pragma unroll
    for (int c = 0; c < 4; ++c) {
        float v = b1[c];
#pragma unroll
        for (int j = 0; j < 16; ++j) v += H[j] * W1[j * 4 + c];  // only rows 0..15 of W1 matter
        hid[c] = fmaxf(v, 0.f);
    }
#pragma unroll
    for (int o = 0; o < 8; ++o) {
        float v = b2[o];
#pragma unroll
        for (int c = 0; c < 4; ++c) v += hid[c] * W2[c * 8 + o];
        out[(size_t)r * 8 + o] = v;
    }
}

extern "C" void kernel_launch(void* const* d_in, const int* in_sizes, int n_in,
                              void* d_out, int out_size, void* d_ws, size_t ws_size,
                              hipStream_t stream) {
    const float* x    = (const float*)d_in[0];
    const int*   ei   = (const int*)d_in[1];
    const float* ea   = (const float*)d_in[2];
    const float* Wl   = (const float*)d_in[3];
    const float* bl   = (const float*)d_in[4];
    const float* Wr   = (const float*)d_in[5];
    const float* br   = (const float*)d_in[6];
    const float* We   = (const float*)d_in[7];
    const float* att  = (const float*)d_in[8];
    const float* gatb = (const float*)d_in[9];
    const float* chW  = (const float*)d_in[10];  // [6][4][16][16]
    const float* chb  = (const float*)d_in[11];  // [6][16]
    const float* W1   = (const float*)d_in[12];
    const float* b1   = (const float*)d_in[13];
    const float* W2   = (const float*)d_in[14];
    const float* b2   = (const float*)d_in[15];
    float* out = (float*)d_out;

    char* w = (char*)d_ws;
    size_t off = 0;
    auto alloc = [&](size_t elems) {
        off = (off + 15) & ~(size_t)15;       // keep float4 alignment
        void* p = w + off;
        off += elems * 4;
        return p;
    };
    int*   cnt_in  = (int*)alloc(N);          // | zeroed region (3N ints,
    int*   deg_out = (int*)alloc(N);          // |  contiguous: cnt_in/deg_out/ctr)
    int*   ctr     = (int*)alloc(N);          // |
    int*   rowptr  = (int*)alloc(N + 2);
    float* xl      = (float*)alloc(16 * N);
    float* xr      = (float*)alloc(16 * N);
    int*   ssrc    = (int*)alloc(E);
    int*   seid    = (int*)alloc(E);
    float* salpha  = (float*)alloc(E);
    float* dinv    = (float*)alloc(N);
    float* h       = (float*)alloc(16 * N);
    float* hs      = (float*)alloc(16 * N);   // dinv-scaled h
    float* accz    = (float*)alloc(16 * N);
    float* acch    = (float*)alloc(16 * N);
    float* T1      = (float*)alloc(16 * N);   // unscaled T1 (Tprev for step 3)
    float* Tsa     = (float*)alloc(16 * N);   // scaled current
    float* Tsb     = (float*)alloc(16 * N);
    (void)ws_size; (void)in_sizes; (void)n_in; (void)out_size;

    hipMemsetAsync(cnt_in, 0, (size_t)3 * N * sizeof(int), stream);

    k_node_transform<<<N / 16, 256, 0, stream>>>(x, Wl, bl, Wr, br, xl, xr);
    k_hist<<<E / 256, 256, 0, stream>>>(ei, cnt_in, deg_out);
    k_scan<<<1, 1024, 0, stream>>>(cnt_in, rowptr, N);
    k_edge_alpha<<<E / 256, 256, 0, stream>>>(ei, ea, xl, xr, We, att, rowptr, ctr,
                                              ssrc, salpha, seid);
    // cheb_W block k of cheb index i is at (i*4+k)*256 ; i=0 -> z path, i=4 -> h path
    k_gat<<<N / 16, 256, 0, stream>>>(rowptr, ssrc, seid, salpha, ea, xl, xr, We, att,
                                      deg_out, gatb, chW + 0 * 256, chW + 16 * 256,
                                      h, hs, accz, acch, dinv);
    // T1 = L h            ; acc += T1@W[1]   (store T1 unscaled + scaled)
    k_mvcomb<<<N / 16, 256, 0, stream>>>(rowptr, ssrc, dinv, hs, (const float*)nullptr,
                                         T1, Tsa, chW + 1 * 256, chW + 17 * 256,
                                         accz, acch, 0);
    // T2 = 2 L T1 - h     ; acc += T2@W[2]   (store scaled only)
    k_mvcomb<<<N / 16, 256, 0, stream>>>(rowptr, ssrc, dinv, Tsa, h,
                                         (float*)nullptr, Tsb, chW + 2 * 256, chW + 18 * 256,
                                         accz, acch, 1);
    // T3 = 2 L T2 - T1    ; acc += T3@W[3]   (no store)
    k_mvcomb<<<N / 16, 256, 0, stream>>>(rowptr, ssrc, dinv, Tsb, T1,
                                         (float*)nullptr, (float*)nullptr,
                                         chW + 3 * 256, chW + 19 * 256, accz, acch, 1);
    k_final<<<(N + 1 + 255) / 256, 256, 0, stream>>>(accz, acch, chb, W1, b1, W2, b2, out);
}